// Round 1
// 405.720 us; speedup vs baseline: 1.1733x; 1.1733x over previous
//
#include <hip/hip_runtime.h>
#include <hip/hip_bf16.h>
#include <cstdint>
#include <cstddef>

// Problem dims (fixed by the reference)
#define T_STEPS 2048
#define BATCH   8
#define D_DIM   1024
#define M_ROWS  (T_STEPS * BATCH)   // 16384 rows of x
#define N_COLS  (2 * D_DIM)         // 2048: W_alpha rows ++ W_x rows
#define K_DIM   D_DIM               // 1024
#define NCH     (BATCH * D_DIM)     // 8192 independent recurrence channels

// GEMM tiling (m97 pattern: unpadded LDS, global_load_lds staging)
#define BM 128
#define BN 128
#define BK 32

typedef __bf16 bf16x8 __attribute__((ext_vector_type(8)));
typedef float  f32x4  __attribute__((ext_vector_type(4)));

__device__ __forceinline__ unsigned short f2bf_rne(float f) {
    union { float f; unsigned u; } c; c.f = f;
    unsigned u = c.u;
    u += 0x7fffu + ((u >> 16) & 1u);   // round-to-nearest-even (inputs finite)
    return (unsigned short)(u >> 16);
}

__device__ __forceinline__ float sigmoid_f(float z) {
    return 1.0f / (1.0f + __expf(-z));
}

// async global -> LDS DMA, 16 B per lane; LDS dest = wave-uniform base + lane*16
__device__ __forceinline__ void glds16(const void* gptr, void* lptr) {
    __builtin_amdgcn_global_load_lds(
        (const __attribute__((address_space(1))) unsigned int*)gptr,
        (__attribute__((address_space(3))) unsigned int*)lptr,
        16, 0, 0);
}

// ---------------------------------------------------------------------------
// fp32 -> bf16 convert (vectorized x4)
// ---------------------------------------------------------------------------
__global__ void cvt_bf16_kernel(const float* __restrict__ src,
                                unsigned short* __restrict__ dst, int n4) {
    int i = blockIdx.x * blockDim.x + threadIdx.x;
    if (i >= n4) return;
    float4 v = reinterpret_cast<const float4*>(src)[i];
    ushort4 o;
    o.x = f2bf_rne(v.x); o.y = f2bf_rne(v.y);
    o.z = f2bf_rne(v.z); o.w = f2bf_rne(v.w);
    reinterpret_cast<ushort4*>(dst)[i] = o;
}

// ---------------------------------------------------------------------------
// Fused bf16 MFMA GEMM (m97 structure): out[m,n] = sum_k x[m,k] * Wc[n,k]
//   n <  1024 -> alpha_out[m,n]   = sigmoid(acc + b_alpha[n])
//   n >= 1024 -> wx_out[m,n-1024] = acc + b[n-1024]
// 256 thr = 4 waves; tile 128x128, BK=32; wave = 64x64 (4x4 MFMA tiles).
// Staging via global_load_lds width=16: wave w, instr p stages 16-row segment
// seg = w*2+p: lane l -> global row seg*16 + l/4, cols (l&3)*8..+7;
// LDS dest = seg*512 shorts + l*8 shorts  ==> row-major [128][32] unpadded.
// ---------------------------------------------------------------------------
__global__ __launch_bounds__(256, 2)
void gemm_kernel(const unsigned short* __restrict__ A,   // [M][K] bf16 (x)
                 const unsigned short* __restrict__ Bm,  // [N][K] bf16 (W_alpha ++ W_x)
                 const float* __restrict__ b_alpha,      // [D]
                 const float* __restrict__ b_x,          // [D]
                 float* __restrict__ alpha_out,          // [M][D] fp32
                 float* __restrict__ wx_out)             // [M][D] fp32
{
    __shared__ unsigned short sA[BM * BK];   // 8 KB
    __shared__ unsigned short sB[BN * BK];   // 8 KB

    const int tid  = threadIdx.x;
    const int wave = tid >> 6;
    const int lane = tid & 63;
    const int rowBase = blockIdx.y * BM;
    const int colBase = blockIdx.x * BN;
    const int wr = (wave >> 1) * 64;
    const int wc = (wave & 1) * 64;

    const int laneHi = lane >> 4;           // 0..3
    const int laneLo = lane & 15;

    // DMA staging addresses (per lane): row sub-offset + col offset
    const int dRow = lane >> 2;             // 0..15
    const int dCol = (lane & 3) * 8;        // 0,8,16,24

    f32x4 acc[4][4];
#pragma unroll
    for (int i = 0; i < 4; i++)
#pragma unroll
        for (int j = 0; j < 4; j++)
            acc[i][j] = (f32x4)(0.0f);

    for (int k0 = 0; k0 < K_DIM; k0 += BK) {
#pragma unroll
        for (int p = 0; p < 2; ++p) {
            const int seg = wave * 2 + p;   // 16-row segment index, 0..7
            glds16(A + (size_t)(rowBase + seg * 16 + dRow) * K_DIM + k0 + dCol,
                   &sA[seg * 512]);
            glds16(Bm + (size_t)(colBase + seg * 16 + dRow) * K_DIM + k0 + dCol,
                   &sB[seg * 512]);
        }
        __syncthreads();   // compiler drains vmcnt(0) here -> LDS tiles ready

        bf16x8 af[4], bfr[4];
#pragma unroll
        for (int i = 0; i < 4; i++)
            af[i] = *reinterpret_cast<const bf16x8*>(
                &sA[(wr + i * 16 + laneLo) * BK + laneHi * 8]);
#pragma unroll
        for (int j = 0; j < 4; j++)
            bfr[j] = *reinterpret_cast<const bf16x8*>(
                &sB[(wc + j * 16 + laneLo) * BK + laneHi * 8]);
        __syncthreads();   // fragments in regs; LDS free for next k-step

#pragma unroll
        for (int i = 0; i < 4; i++)
#pragma unroll
            for (int j = 0; j < 4; j++)
                acc[i][j] = __builtin_amdgcn_mfma_f32_16x16x32_bf16(
                    af[i], bfr[j], acc[i][j], 0, 0, 0);
    }

    // Epilogue. C/D layout: col = lane&15, row = (lane>>4)*4 + reg  [m89/m91]
#pragma unroll
    for (int i = 0; i < 4; i++) {
        int row = rowBase + wr + i * 16 + laneHi * 4;
#pragma unroll
        for (int j = 0; j < 4; j++) {
            int col = colBase + wc + j * 16 + laneLo;
            if (col < D_DIM) {
                float bias = b_alpha[col];
#pragma unroll
                for (int r = 0; r < 4; r++) {
                    float z = acc[i][j][r] + bias;
                    alpha_out[(size_t)(row + r) * D_DIM + col] = sigmoid_f(z);
                }
            } else {
                int c2 = col - D_DIM;
                float bias = b_x[c2];
#pragma unroll
                for (int r = 0; r < 4; r++)
                    wx_out[(size_t)(row + r) * D_DIM + c2] = acc[i][j][r] + bias;
            }
        }
    }
}

// ---------------------------------------------------------------------------
// Sequential scan, producer-consumer, 2 channels per lane (ILP=2):
//   64 blocks x 128 thr. Wave 0 computes 128 channels (2/lane); wave 1 DMA-
//   stages 32-timestep tiles of alpha/wx into double-buffered LDS.
// Recurrence refactored to a 5-op cross-step dependent chain:
//   u = 1-a (off-chain); p = C*h + C*w (fma, C=2*log2e); e = exp2(p);
//   r = rcp(e+1); m = a*h+u (fma, parallel with exp chain);
//   h' = m - 2u*r (fma).   [== a*h + (1-a)*tanh(h+w)]
// out = h^2*sigmoid(h) is NOT on the chain -> moved to out_kernel (parallel).
// LDS per tile buffer: row-major [TT][128] fp32; glds16 p stages timesteps
// 2p,2p+1 (lane l -> ts 2p + l/32, ch (l&31)*4).
// ---------------------------------------------------------------------------
#define TT 32
#define NT (T_STEPS / TT)   // 64 tiles
#define CPB 128             // channels per block (2 per lane)

__global__ __launch_bounds__(128)
void scan_kernel(const float* __restrict__ alpha,  // [T][NCH]
                 const float* __restrict__ wx,     // [T][NCH]
                 const float* __restrict__ h0,     // [NCH]
                 float* __restrict__ hout)         // [T+1][NCH]
{
    __shared__ float sAl[2][TT * CPB];   // 2 x 16 KB
    __shared__ float sWx[2][TT * CPB];   // 2 x 16 KB

    const int lane = threadIdx.x & 63;
    const int wave = threadIdx.x >> 6;
    const int ch0  = blockIdx.x * CPB;

    // producer lane mapping for glds16 (16 B = 4 floats per lane)
    const int q  = lane >> 5;          // sub-timestep 0..1 within instr
    const int c4 = (lane & 31) * 4;    // channel group

    const float C2L = 2.88539008177792681472f;   // 2*log2(e)

    float hA = 0.0f, hB = 0.0f;

    if (wave == 1) {
        // producer: stage tile 0 into buffer 0
#pragma unroll
        for (int p = 0; p < TT / 2; ++p) {
            const size_t g = (size_t)(p * 2 + q) * NCH + ch0 + c4;
            glds16(alpha + g, &sAl[0][p * 256]);
            glds16(wx    + g, &sWx[0][p * 256]);
        }
    } else {
        const float2 h2 = *reinterpret_cast<const float2*>(&h0[ch0 + 2 * lane]);
        hA = h2.x; hB = h2.y;
        *reinterpret_cast<float2*>(&hout[ch0 + 2 * lane]) = h2;
    }
    __syncthreads();   // tile 0 staged

    for (int tile = 0; tile < NT; ++tile) {
        const int cur = tile & 1;
        if (wave == 1) {
            if (tile + 1 < NT) {
                const int t0 = (tile + 1) * TT;
#pragma unroll
                for (int p = 0; p < TT / 2; ++p) {
                    const size_t g = (size_t)(t0 + p * 2 + q) * NCH + ch0 + c4;
                    glds16(alpha + g, &sAl[cur ^ 1][p * 256]);
                    glds16(wx    + g, &sWx[cur ^ 1][p * 256]);
                }
            }
        } else {
            const int tbase = tile * TT;
#pragma unroll 16
            for (int ts = 0; ts < TT; ++ts) {
                const float2 a2 = *reinterpret_cast<const float2*>(
                    &sAl[cur][ts * CPB + 2 * lane]);
                const float2 w2 = *reinterpret_cast<const float2*>(
                    &sWx[cur][ts * CPB + 2 * lane]);
                // channel A: chain = fma -> exp2 -> add -> rcp -> fma
                const float uA = 1.0f - a2.x;
                const float pA = fmaf(hA, C2L, w2.x * C2L);
                const float eA = __builtin_amdgcn_exp2f(pA);
                const float rA = __builtin_amdgcn_rcpf(eA + 1.0f);
                const float mA = fmaf(a2.x, hA, uA);
                hA = fmaf(-(uA + uA), rA, mA);
                // channel B (independent chain fills A's stall slots)
                const float uB = 1.0f - a2.y;
                const float pB = fmaf(hB, C2L, w2.y * C2L);
                const float eB = __builtin_amdgcn_exp2f(pB);
                const float rB = __builtin_amdgcn_rcpf(eB + 1.0f);
                const float mB = fmaf(a2.y, hB, uB);
                hB = fmaf(-(uB + uB), rB, mB);

                const int t = tbase + ts;
                *reinterpret_cast<float2*>(
                    &hout[(size_t)(t + 1) * NCH + ch0 + 2 * lane]) =
                    make_float2(hA, hB);
            }
        }
        __syncthreads();   // next tile staged AND current buffer consumed
    }
}

// ---------------------------------------------------------------------------
// out[t] = h_{t+1}^2 * sigmoid(h_{t+1})  == h*silu(h), fully parallel.
// Linear view: out[j] = f(hout[j + NCH]) for j in [0, T*NCH).
// ---------------------------------------------------------------------------
__global__ __launch_bounds__(256)
void out_kernel(const float* __restrict__ hnext,   // hout + NCH
                float* __restrict__ out, int n4) {
    const float L2E = 1.44269504088896340736f;
    int stride = gridDim.x * blockDim.x;
    for (int i = blockIdx.x * blockDim.x + threadIdx.x; i < n4; i += stride) {
        float4 h = reinterpret_cast<const float4*>(hnext)[i];
        float4 o;
        o.x = h.x * h.x * __builtin_amdgcn_rcpf(1.0f + __builtin_amdgcn_exp2f(-L2E * h.x));
        o.y = h.y * h.y * __builtin_amdgcn_rcpf(1.0f + __builtin_amdgcn_exp2f(-L2E * h.y));
        o.z = h.z * h.z * __builtin_amdgcn_rcpf(1.0f + __builtin_amdgcn_exp2f(-L2E * h.z));
        o.w = h.w * h.w * __builtin_amdgcn_rcpf(1.0f + __builtin_amdgcn_exp2f(-L2E * h.w));
        reinterpret_cast<float4*>(out)[i] = o;
    }
}

// ---------------------------------------------------------------------------
extern "C" void kernel_launch(void* const* d_in, const int* in_sizes, int n_in,
                              void* d_out, int out_size, void* d_ws, size_t ws_size,
                              hipStream_t stream) {
    const float* x       = (const float*)d_in[0];  // [T,B,D]
    const float* h0      = (const float*)d_in[1];  // [B,D]
    const float* W_alpha = (const float*)d_in[2];  // [D,D]
    const float* b_alpha = (const float*)d_in[3];  // [D]
    const float* W_x     = (const float*)d_in[4];  // [D,D]
    const float* b       = (const float*)d_in[5];  // [D]

    float* out  = (float*)d_out;                              // [T,B,D]
    float* hout = out + (size_t)T_STEPS * BATCH * D_DIM;      // [T+1,B,D]

    // Workspace layout (~164 MB):
    //   alpha fp32 (64 MB) | wx fp32 (64 MB) | x bf16 (32 MB) | Wc bf16 (4 MB)
    float* ws_alpha = (float*)d_ws;
    float* ws_wx    = ws_alpha + (size_t)M_ROWS * D_DIM;
    unsigned short* ws_x = (unsigned short*)(ws_wx + (size_t)M_ROWS * D_DIM);
    unsigned short* ws_W = ws_x + (size_t)M_ROWS * K_DIM;

    // 1) convert x, W_alpha, W_x to bf16
    {
        int n4 = M_ROWS * K_DIM / 4;
        cvt_bf16_kernel<<<(n4 + 255) / 256, 256, 0, stream>>>(x, ws_x, n4);
    }
    {
        int n4 = D_DIM * K_DIM / 4;
        cvt_bf16_kernel<<<(n4 + 255) / 256, 256, 0, stream>>>(W_alpha, ws_W, n4);
        cvt_bf16_kernel<<<(n4 + 255) / 256, 256, 0, stream>>>(
            W_x, ws_W + (size_t)D_DIM * K_DIM, n4);
    }

    // 2) fused GEMM (N = 2048 covers both projections) + bias + sigmoid epilogue
    {
        dim3 grid(N_COLS / BN, M_ROWS / BM);   // (16, 128)
        gemm_kernel<<<grid, 256, 0, stream>>>(ws_x, ws_W, b_alpha, b,
                                              ws_alpha, ws_wx);
    }

    // 3) sequential scan: 64 blocks x (1 compute wave + 1 DMA wave), 2 ch/lane
    scan_kernel<<<NCH / CPB, 128, 0, stream>>>(ws_alpha, ws_wx, h0, hout);

    // 4) out = h*silu(h), massively parallel from hout (shifted one row)
    {
        int n4 = (int)((size_t)T_STEPS * NCH / 4);
        out_kernel<<<2048, 256, 0, stream>>>(hout + NCH, out, n4);
    }
}